// Round 1
// baseline (5476.370 us; speedup 1.0000x reference)
//
#include <hip/hip_runtime.h>

#define N_ATOMS 100000
#define N_EDGES 3200000
#define N_RBF 8
#define HIDDEN 16

// d_out layout (floats):
//  [0]                      total_energy_local (1,)
//  [1            .. 100001) node_energy (N,)
//  [100001       .. 400001) forces (N,3)
//  [400001       .. 400010) virials (3,3)
//  [400010       ..1300010) atom_virial (N,3,3)
#define OFF_TE   0
#define OFF_NE   1
#define OFF_F    (1 + N_ATOMS)
#define OFF_VIR  (1 + N_ATOMS + 3*N_ATOMS)
#define OFF_AV   (OFF_VIR + 9)

__global__ void edge_forward(const float* __restrict__ vectors,
                             const int*   __restrict__ edge_index,
                             const float* __restrict__ W1,
                             const float* __restrict__ b1,
                             const float* __restrict__ alphas,
                             float* __restrict__ h) {
    int e = blockIdx.x * blockDim.x + threadIdx.x;
    if (e >= N_EDGES) return;
    float vx = vectors[3*e + 0];
    float vy = vectors[3*e + 1];
    float vz = vectors[3*e + 2];
    float r2 = vx*vx + vy*vy + vz*vz;
    float phi[N_RBF];
    #pragma unroll
    for (int f = 0; f < N_RBF; ++f) phi[f] = __expf(-r2 * alphas[f]);
    int recv = edge_index[N_EDGES + e];
    float* hr = h + recv * HIDDEN;
    #pragma unroll
    for (int j = 0; j < HIDDEN; ++j) {
        float pre = b1[j];
        #pragma unroll
        for (int f = 0; f < N_RBF; ++f) pre += phi[f] * W1[f*HIDDEN + j];
        float sig = 1.0f / (1.0f + __expf(-pre));
        atomicAdd(&hr[j], pre * sig);   // msg = silu(pre)
    }
}

__global__ void node_pass(const float* __restrict__ positions,
                          const float* __restrict__ lg,
                          const float* __restrict__ W2,
                          const float* __restrict__ w3,
                          const float* __restrict__ field,
                          float* __restrict__ h,          // in: h, out: gh (in-place)
                          float* __restrict__ out) {
    int n = blockIdx.x * blockDim.x + threadIdx.x;
    float contrib = 0.0f;
    if (n < N_ATOMS) {
        float hl[HIDDEN];
        const float4* hp = (const float4*)(h + n*HIDDEN);
        #pragma unroll
        for (int q = 0; q < 4; ++q) {
            float4 v = hp[q];
            hl[4*q+0] = v.x; hl[4*q+1] = v.y; hl[4*q+2] = v.z; hl[4*q+3] = v.w;
        }
        float a[HIDDEN];
        #pragma unroll
        for (int j = 0; j < HIDDEN; ++j) {
            float acc = 0.0f;
            #pragma unroll
            for (int i = 0; i < HIDDEN; ++i) acc += hl[i] * W2[i*HIDDEN + j];
            a[j] = acc;
        }
        float l = lg[n];
        float sdot = 0.0f;
        float dA[HIDDEN];
        #pragma unroll
        for (int j = 0; j < HIDDEN; ++j) {
            float sig = 1.0f / (1.0f + __expf(-a[j]));
            sdot += a[j] * sig * w3[j];                       // silu(a)·w3
            dA[j] = l * w3[j] * sig * (1.0f + a[j]*(1.0f - sig)); // dE/da
        }
        float ne = sdot + positions[3*n+0]*field[0]
                        + positions[3*n+1]*field[1]
                        + positions[3*n+2]*field[2];
        out[OFF_NE + n] = ne;
        out[OFF_F + 3*n + 0] = -l * field[0];
        out[OFF_F + 3*n + 1] = -l * field[1];
        out[OFF_F + 3*n + 2] = -l * field[2];
        // gh[i] = sum_j dA[j] * W2[i,j]  (overwrite h in place)
        float4* gp = (float4*)(h + n*HIDDEN);
        #pragma unroll
        for (int q = 0; q < 4; ++q) {
            float g0 = 0.0f, g1 = 0.0f, g2 = 0.0f, g3 = 0.0f;
            #pragma unroll
            for (int j = 0; j < HIDDEN; ++j) {
                g0 += dA[j] * W2[(4*q+0)*HIDDEN + j];
                g1 += dA[j] * W2[(4*q+1)*HIDDEN + j];
                g2 += dA[j] * W2[(4*q+2)*HIDDEN + j];
                g3 += dA[j] * W2[(4*q+3)*HIDDEN + j];
            }
            gp[q] = make_float4(g0, g1, g2, g3);
        }
        contrib = ne * l;
    }
    // block reduction of total energy
    __shared__ float red[4];
    int lane = threadIdx.x & 63, wid = threadIdx.x >> 6;
    #pragma unroll
    for (int o = 32; o > 0; o >>= 1) contrib += __shfl_down(contrib, o);
    if (lane == 0) red[wid] = contrib;
    __syncthreads();
    if (threadIdx.x == 0) {
        float s = red[0] + red[1] + red[2] + red[3];
        atomicAdd(&out[OFF_TE], s);
    }
}

__global__ void edge_backward(const float* __restrict__ vectors,
                              const int*   __restrict__ edge_index,
                              const float* __restrict__ W1,
                              const float* __restrict__ b1,
                              const float* __restrict__ alphas,
                              const float* __restrict__ gh,
                              float* __restrict__ out) {
    int e = blockIdx.x * blockDim.x + threadIdx.x;
    if (e >= N_EDGES) return;
    float vx = vectors[3*e + 0];
    float vy = vectors[3*e + 1];
    float vz = vectors[3*e + 2];
    float r2 = vx*vx + vy*vy + vz*vz;
    float phi[N_RBF];
    #pragma unroll
    for (int f = 0; f < N_RBF; ++f) phi[f] = __expf(-r2 * alphas[f]);
    int send = edge_index[e];
    int recv = edge_index[N_EDGES + e];
    float g[HIDDEN];
    const float4* gp = (const float4*)(gh + recv*HIDDEN);
    #pragma unroll
    for (int q = 0; q < 4; ++q) {
        float4 v = gp[q];
        g[4*q+0] = v.x; g[4*q+1] = v.y; g[4*q+2] = v.z; g[4*q+3] = v.w;
    }
    float dphi[N_RBF];
    #pragma unroll
    for (int f = 0; f < N_RBF; ++f) dphi[f] = 0.0f;
    #pragma unroll
    for (int j = 0; j < HIDDEN; ++j) {
        float pre = b1[j];
        #pragma unroll
        for (int f = 0; f < N_RBF; ++f) pre += phi[f] * W1[f*HIDDEN + j];
        float sig = 1.0f / (1.0f + __expf(-pre));
        float dpre = g[j] * sig * (1.0f + pre*(1.0f - sig));
        #pragma unroll
        for (int f = 0; f < N_RBF; ++f) dphi[f] += dpre * W1[f*HIDDEN + j];
    }
    float dr2 = 0.0f;
    #pragma unroll
    for (int f = 0; f < N_RBF; ++f) dr2 -= dphi[f] * alphas[f] * phi[f];
    // edge_forces = -2*dr2*v ; edge_virial ev_ij = ef_i*v_j (symmetric)
    // atom_virial gets -0.5*ev added at both sender and receiver
    float m = dr2;  // -0.5 * (-2*dr2) = dr2
    float v3[3] = {vx, vy, vz};
    #pragma unroll
    for (int i = 0; i < 3; ++i) {
        #pragma unroll
        for (int j = 0; j < 3; ++j) {
            float val = m * v3[i] * v3[j];
            atomicAdd(&out[OFF_AV + send*9 + i*3 + j], val);
            atomicAdd(&out[OFF_AV + recv*9 + i*3 + j], val);
        }
    }
}

__global__ void virial_reduce(float* __restrict__ out) {
    const float* av = out + OFF_AV;
    float acc[9];
    #pragma unroll
    for (int c = 0; c < 9; ++c) acc[c] = 0.0f;
    for (int n = blockIdx.x * blockDim.x + threadIdx.x; n < N_ATOMS;
         n += gridDim.x * blockDim.x) {
        #pragma unroll
        for (int c = 0; c < 9; ++c) acc[c] += av[n*9 + c];
    }
    __shared__ float red[4];
    int lane = threadIdx.x & 63, wid = threadIdx.x >> 6;
    #pragma unroll
    for (int c = 0; c < 9; ++c) {
        float v = acc[c];
        #pragma unroll
        for (int o = 32; o > 0; o >>= 1) v += __shfl_down(v, o);
        if (lane == 0) red[wid] = v;
        __syncthreads();
        if (threadIdx.x == 0) atomicAdd(&out[OFF_VIR + c], red[0]+red[1]+red[2]+red[3]);
        __syncthreads();
    }
}

extern "C" void kernel_launch(void* const* d_in, const int* in_sizes, int n_in,
                              void* d_out, int out_size, void* d_ws, size_t ws_size,
                              hipStream_t stream) {
    const float* positions = (const float*)d_in[0];
    const float* vectors   = (const float*)d_in[1];
    const float* lg        = (const float*)d_in[2];
    const float* W1        = (const float*)d_in[3];
    const float* b1        = (const float*)d_in[4];
    const float* W2        = (const float*)d_in[5];
    const float* w3        = (const float*)d_in[6];
    const float* field     = (const float*)d_in[7];
    const float* alphas    = (const float*)d_in[8];
    const int*   edge_index= (const int*)  d_in[9];
    float* out = (float*)d_out;
    float* h   = (float*)d_ws;   // N_ATOMS*HIDDEN floats (6.4 MB)

    // zero accumulators: h, total_energy, virials+atom_virial
    hipMemsetAsync(h, 0, (size_t)N_ATOMS * HIDDEN * sizeof(float), stream);
    hipMemsetAsync(out + OFF_TE, 0, sizeof(float), stream);
    hipMemsetAsync(out + OFF_VIR, 0, (size_t)(9 + 9*N_ATOMS) * sizeof(float), stream);

    dim3 blk(256);
    dim3 egrid((N_EDGES + 255) / 256);
    dim3 ngrid((N_ATOMS + 255) / 256);

    edge_forward<<<egrid, blk, 0, stream>>>(vectors, edge_index, W1, b1, alphas, h);
    node_pass<<<ngrid, blk, 0, stream>>>(positions, lg, W2, w3, field, h, out);
    edge_backward<<<egrid, blk, 0, stream>>>(vectors, edge_index, W1, b1, alphas, h, out);
    virial_reduce<<<dim3(256), blk, 0, stream>>>(out);
}

// Round 2
// 1310.900 us; speedup vs baseline: 4.1776x; 4.1776x over previous
//
#include <hip/hip_runtime.h>

#define N_ATOMS 100000
#define N_EDGES 3200000
#define N_RBF 8
#define HIDDEN 16

// d_out layout (floats):
#define OFF_TE   0
#define OFF_NE   1
#define OFF_F    (1 + N_ATOMS)
#define OFF_VIR  (1 + N_ATOMS + 3*N_ATOMS)
#define OFF_AV   (OFF_VIR + 9)

// ws layout (4-byte words)
#define WPAD        (N_ATOMS + 4)
#define WOFF_OFFS_R 0
#define WOFF_OFFS_S WPAD
#define WOFF_RANK_R (2*WPAD)
#define WOFF_RANK_S (WOFF_RANK_R + N_EDGES)
#define WOFF_EID_R  (WOFF_RANK_S + N_EDGES)
#define WOFF_EID_S  (WOFF_EID_R + N_EDGES)
#define WOFF_DR2    (WOFF_EID_S + N_EDGES)
#define WOFF_GH     (WOFF_DR2 + N_EDGES)
#define WOFF_AV6    (WOFF_GH + 16*N_ATOMS)
#define WOFF_END    (WOFF_AV6 + 6*N_ATOMS)

// ---------------- CSR build ----------------

__global__ void count_kernel(const int* __restrict__ ei,
                             int* __restrict__ cnt_r, int* __restrict__ cnt_s,
                             int* __restrict__ rank_r, int* __restrict__ rank_s) {
    int e = blockIdx.x * blockDim.x + threadIdx.x;
    if (e >= N_EDGES) return;
    int send = ei[e], recv = ei[N_EDGES + e];
    rank_r[e] = atomicAdd(&cnt_r[recv], 1);
    rank_s[e] = atomicAdd(&cnt_s[send], 1);
}

__global__ void scan_kernel(int* __restrict__ offs_r, int* __restrict__ offs_s) {
    int* a = (blockIdx.x == 0) ? offs_r : offs_s;
    const int n = N_ATOMS + 1;
    __shared__ int wsum[4];
    __shared__ int carry_s;
    if (threadIdx.x == 0) carry_s = 0;
    __syncthreads();
    int lane = threadIdx.x & 63, w = threadIdx.x >> 6;
    for (int base = 0; base < n; base += 256) {
        int i = base + threadIdx.x;
        int v = (i < n) ? a[i] : 0;
        int s = v;
        #pragma unroll
        for (int o = 1; o < 64; o <<= 1) {
            int t = __shfl_up(s, o);
            if (lane >= o) s += t;
        }
        if (lane == 63) wsum[w] = s;
        __syncthreads();
        int wpre = 0;
        for (int k = 0; k < w; ++k) wpre += wsum[k];
        int incl = s + wpre;
        int total = wsum[0] + wsum[1] + wsum[2] + wsum[3];
        int excl = incl - v + carry_s;
        if (i < n) a[i] = excl;
        __syncthreads();
        if (threadIdx.x == 0) carry_s += total;
        __syncthreads();
    }
}

__global__ void scatter_kernel(const int* __restrict__ ei,
                               const int* __restrict__ offs_r, const int* __restrict__ offs_s,
                               const int* __restrict__ rank_r, const int* __restrict__ rank_s,
                               int* __restrict__ eid_r, int* __restrict__ eid_s) {
    int e = blockIdx.x * blockDim.x + threadIdx.x;
    if (e >= N_EDGES) return;
    int send = ei[e], recv = ei[N_EDGES + e];
    eid_r[offs_r[recv] + rank_r[e]] = e;
    eid_s[offs_s[send] + rank_s[e]] = e;
}

// ---------------- fused forward gather + node MLP ----------------

__global__ void fwd_node_kernel(const float* __restrict__ vectors,
                                const float* __restrict__ positions,
                                const float* __restrict__ lg,
                                const float* __restrict__ W1, const float* __restrict__ b1,
                                const float* __restrict__ W2, const float* __restrict__ w3,
                                const float* __restrict__ field, const float* __restrict__ alphas,
                                const int* __restrict__ offs_r, const int* __restrict__ eid_r,
                                float* __restrict__ gh, float* __restrict__ out) {
    int a = (blockIdx.x * blockDim.x + threadIdx.x) >> 6;   // one wave per atom
    int lane = threadIdx.x & 63;
    int start = offs_r[a], end = offs_r[a + 1];
    float al[N_RBF];
    #pragma unroll
    for (int f = 0; f < N_RBF; ++f) al[f] = alphas[f];
    float m[HIDDEN];
    #pragma unroll
    for (int j = 0; j < HIDDEN; ++j) m[j] = 0.f;
    for (int k = start + lane; k < end; k += 64) {
        int e = eid_r[k];
        float vx = vectors[3*e], vy = vectors[3*e+1], vz = vectors[3*e+2];
        float r2 = vx*vx + vy*vy + vz*vz;
        float phi[N_RBF];
        #pragma unroll
        for (int f = 0; f < N_RBF; ++f) phi[f] = __expf(-r2 * al[f]);
        #pragma unroll
        for (int j = 0; j < HIDDEN; ++j) {
            float pre = b1[j];
            #pragma unroll
            for (int f = 0; f < N_RBF; ++f) pre += phi[f] * W1[f*HIDDEN + j];
            float sig = 1.f / (1.f + __expf(-pre));
            m[j] += pre * sig;
        }
    }
    #pragma unroll
    for (int o = 1; o < 64; o <<= 1) {
        #pragma unroll
        for (int j = 0; j < HIDDEN; ++j) m[j] += __shfl_xor(m[j], o);
    }
    // node MLP (redundant across lanes; cheap)
    float l = lg[a];
    float sdot = 0.f;
    float dA[HIDDEN];
    #pragma unroll
    for (int j = 0; j < HIDDEN; ++j) {
        float acc = 0.f;
        #pragma unroll
        for (int i = 0; i < HIDDEN; ++i) acc += m[i] * W2[i*HIDDEN + j];
        float sig = 1.f / (1.f + __expf(-acc));
        sdot += acc * sig * w3[j];
        dA[j] = l * w3[j] * sig * (1.f + acc * (1.f - sig));
    }
    float contrib = 0.f;
    if (lane == 0) {
        float ne = sdot + positions[3*a]*field[0] + positions[3*a+1]*field[1]
                        + positions[3*a+2]*field[2];
        out[OFF_NE + a] = ne;
        out[OFF_F + 3*a + 0] = -l * field[0];
        out[OFF_F + 3*a + 1] = -l * field[1];
        out[OFF_F + 3*a + 2] = -l * field[2];
        contrib = ne * l;
        float g[HIDDEN];
        #pragma unroll
        for (int i = 0; i < HIDDEN; ++i) {
            float acc = 0.f;
            #pragma unroll
            for (int j = 0; j < HIDDEN; ++j) acc += dA[j] * W2[i*HIDDEN + j];
            g[i] = acc;
        }
        float4* gp = (float4*)(gh + (size_t)a * HIDDEN);
        gp[0] = make_float4(g[0], g[1], g[2], g[3]);
        gp[1] = make_float4(g[4], g[5], g[6], g[7]);
        gp[2] = make_float4(g[8], g[9], g[10], g[11]);
        gp[3] = make_float4(g[12], g[13], g[14], g[15]);
    }
    __shared__ float red[4];
    int w = threadIdx.x >> 6;
    if (lane == 0) red[w] = contrib;
    __syncthreads();
    if (threadIdx.x == 0) atomicAdd(&out[OFF_TE], red[0]+red[1]+red[2]+red[3]);
}

// ---------------- backward: recv-side gather ----------------

__global__ void bwd_recv_kernel(const float* __restrict__ vectors,
                                const float* __restrict__ W1, const float* __restrict__ b1,
                                const float* __restrict__ alphas,
                                const int* __restrict__ offs_r, const int* __restrict__ eid_r,
                                const float* __restrict__ gh,
                                float* __restrict__ dr2buf, float* __restrict__ av6) {
    int a = (blockIdx.x * blockDim.x + threadIdx.x) >> 6;
    int lane = threadIdx.x & 63;
    int start = offs_r[a], end = offs_r[a + 1];
    float g[HIDDEN];
    {
        const float4* gp = (const float4*)(gh + (size_t)a * HIDDEN);
        float4 q0 = gp[0], q1 = gp[1], q2 = gp[2], q3 = gp[3];
        g[0]=q0.x; g[1]=q0.y; g[2]=q0.z; g[3]=q0.w;
        g[4]=q1.x; g[5]=q1.y; g[6]=q1.z; g[7]=q1.w;
        g[8]=q2.x; g[9]=q2.y; g[10]=q2.z; g[11]=q2.w;
        g[12]=q3.x; g[13]=q3.y; g[14]=q3.z; g[15]=q3.w;
    }
    float al[N_RBF];
    #pragma unroll
    for (int f = 0; f < N_RBF; ++f) al[f] = alphas[f];
    float axx=0.f, axy=0.f, axz=0.f, ayy=0.f, ayz=0.f, azz=0.f;
    for (int k = start + lane; k < end; k += 64) {
        int e = eid_r[k];
        float vx = vectors[3*e], vy = vectors[3*e+1], vz = vectors[3*e+2];
        float r2 = vx*vx + vy*vy + vz*vz;
        float phi[N_RBF];
        #pragma unroll
        for (int f = 0; f < N_RBF; ++f) phi[f] = __expf(-r2 * al[f]);
        float dphi[N_RBF];
        #pragma unroll
        for (int f = 0; f < N_RBF; ++f) dphi[f] = 0.f;
        #pragma unroll
        for (int j = 0; j < HIDDEN; ++j) {
            float pre = b1[j];
            #pragma unroll
            for (int f = 0; f < N_RBF; ++f) pre += phi[f] * W1[f*HIDDEN + j];
            float sig = 1.f / (1.f + __expf(-pre));
            float dpre = g[j] * sig * (1.f + pre * (1.f - sig));
            #pragma unroll
            for (int f = 0; f < N_RBF; ++f) dphi[f] += dpre * W1[f*HIDDEN + j];
        }
        float dr2 = 0.f;
        #pragma unroll
        for (int f = 0; f < N_RBF; ++f) dr2 -= dphi[f] * al[f] * phi[f];
        dr2buf[e] = dr2;
        axx += dr2*vx*vx; axy += dr2*vx*vy; axz += dr2*vx*vz;
        ayy += dr2*vy*vy; ayz += dr2*vy*vz; azz += dr2*vz*vz;
    }
    #pragma unroll
    for (int o = 1; o < 64; o <<= 1) {
        axx += __shfl_xor(axx, o); axy += __shfl_xor(axy, o); axz += __shfl_xor(axz, o);
        ayy += __shfl_xor(ayy, o); ayz += __shfl_xor(ayz, o); azz += __shfl_xor(azz, o);
    }
    if (lane == 0) {
        float2* p = (float2*)(av6 + (size_t)a * 6);
        p[0] = make_float2(axx, axy);
        p[1] = make_float2(axz, ayy);
        p[2] = make_float2(ayz, azz);
    }
}

// ---------------- backward: send-side gather + finalize ----------------

__global__ void bwd_send_kernel(const float* __restrict__ vectors,
                                const int* __restrict__ offs_s, const int* __restrict__ eid_s,
                                const float* __restrict__ dr2buf, const float* __restrict__ av6,
                                float* __restrict__ out) {
    int a = (blockIdx.x * blockDim.x + threadIdx.x) >> 6;
    int lane = threadIdx.x & 63;
    int start = offs_s[a], end = offs_s[a + 1];
    float axx=0.f, axy=0.f, axz=0.f, ayy=0.f, ayz=0.f, azz=0.f;
    for (int k = start + lane; k < end; k += 64) {
        int e = eid_s[k];
        float dr2 = dr2buf[e];
        float vx = vectors[3*e], vy = vectors[3*e+1], vz = vectors[3*e+2];
        axx += dr2*vx*vx; axy += dr2*vx*vy; axz += dr2*vx*vz;
        ayy += dr2*vy*vy; ayz += dr2*vy*vz; azz += dr2*vz*vz;
    }
    #pragma unroll
    for (int o = 1; o < 64; o <<= 1) {
        axx += __shfl_xor(axx, o); axy += __shfl_xor(axy, o); axz += __shfl_xor(axz, o);
        ayy += __shfl_xor(ayy, o); ayz += __shfl_xor(ayz, o); azz += __shfl_xor(azz, o);
    }
    if (lane == 0) {
        const float2* p = (const float2*)(av6 + (size_t)a * 6);
        float2 p0 = p[0], p1 = p[1], p2 = p[2];
        axx += p0.x; axy += p0.y; axz += p1.x;
        ayy += p1.y; ayz += p2.x; azz += p2.y;
        float* o9 = out + OFF_AV + (size_t)a * 9;
        o9[0] = axx; o9[1] = axy; o9[2] = axz;
        o9[3] = axy; o9[4] = ayy; o9[5] = ayz;
        o9[6] = axz; o9[7] = ayz; o9[8] = azz;
    }
}

__global__ void virial_reduce(float* __restrict__ out) {
    const float* av = out + OFF_AV;
    float acc[9];
    #pragma unroll
    for (int c = 0; c < 9; ++c) acc[c] = 0.0f;
    for (int n = blockIdx.x * blockDim.x + threadIdx.x; n < N_ATOMS;
         n += gridDim.x * blockDim.x) {
        #pragma unroll
        for (int c = 0; c < 9; ++c) acc[c] += av[n*9 + c];
    }
    __shared__ float red[4];
    int lane = threadIdx.x & 63, wid = threadIdx.x >> 6;
    #pragma unroll
    for (int c = 0; c < 9; ++c) {
        float v = acc[c];
        #pragma unroll
        for (int o = 32; o > 0; o >>= 1) v += __shfl_down(v, o);
        if (lane == 0) red[wid] = v;
        __syncthreads();
        if (threadIdx.x == 0) atomicAdd(&out[OFF_VIR + c], red[0]+red[1]+red[2]+red[3]);
        __syncthreads();
    }
}

// ---------------- fallback (round-1 atomic path) ----------------

__global__ void edge_forward_fb(const float* __restrict__ vectors,
                                const int* __restrict__ edge_index,
                                const float* __restrict__ W1, const float* __restrict__ b1,
                                const float* __restrict__ alphas, float* __restrict__ h) {
    int e = blockIdx.x * blockDim.x + threadIdx.x;
    if (e >= N_EDGES) return;
    float vx = vectors[3*e], vy = vectors[3*e+1], vz = vectors[3*e+2];
    float r2 = vx*vx + vy*vy + vz*vz;
    float phi[N_RBF];
    #pragma unroll
    for (int f = 0; f < N_RBF; ++f) phi[f] = __expf(-r2 * alphas[f]);
    int recv = edge_index[N_EDGES + e];
    float* hr = h + recv * HIDDEN;
    #pragma unroll
    for (int j = 0; j < HIDDEN; ++j) {
        float pre = b1[j];
        #pragma unroll
        for (int f = 0; f < N_RBF; ++f) pre += phi[f] * W1[f*HIDDEN + j];
        float sig = 1.0f / (1.0f + __expf(-pre));
        atomicAdd(&hr[j], pre * sig);
    }
}

__global__ void node_pass_fb(const float* __restrict__ positions,
                             const float* __restrict__ lg,
                             const float* __restrict__ W2, const float* __restrict__ w3,
                             const float* __restrict__ field,
                             float* __restrict__ h, float* __restrict__ out) {
    int n = blockIdx.x * blockDim.x + threadIdx.x;
    float contrib = 0.0f;
    if (n < N_ATOMS) {
        float hl[HIDDEN];
        const float4* hp = (const float4*)(h + n*HIDDEN);
        #pragma unroll
        for (int q = 0; q < 4; ++q) {
            float4 v = hp[q];
            hl[4*q+0]=v.x; hl[4*q+1]=v.y; hl[4*q+2]=v.z; hl[4*q+3]=v.w;
        }
        float a[HIDDEN];
        #pragma unroll
        for (int j = 0; j < HIDDEN; ++j) {
            float acc = 0.0f;
            #pragma unroll
            for (int i = 0; i < HIDDEN; ++i) acc += hl[i] * W2[i*HIDDEN + j];
            a[j] = acc;
        }
        float l = lg[n];
        float sdot = 0.0f;
        float dA[HIDDEN];
        #pragma unroll
        for (int j = 0; j < HIDDEN; ++j) {
            float sig = 1.0f / (1.0f + __expf(-a[j]));
            sdot += a[j] * sig * w3[j];
            dA[j] = l * w3[j] * sig * (1.0f + a[j]*(1.0f - sig));
        }
        float ne = sdot + positions[3*n]*field[0] + positions[3*n+1]*field[1]
                        + positions[3*n+2]*field[2];
        out[OFF_NE + n] = ne;
        out[OFF_F + 3*n + 0] = -l * field[0];
        out[OFF_F + 3*n + 1] = -l * field[1];
        out[OFF_F + 3*n + 2] = -l * field[2];
        float4* gp = (float4*)(h + n*HIDDEN);
        #pragma unroll
        for (int q = 0; q < 4; ++q) {
            float g0=0,g1=0,g2=0,g3=0;
            #pragma unroll
            for (int j = 0; j < HIDDEN; ++j) {
                g0 += dA[j]*W2[(4*q+0)*HIDDEN+j];
                g1 += dA[j]*W2[(4*q+1)*HIDDEN+j];
                g2 += dA[j]*W2[(4*q+2)*HIDDEN+j];
                g3 += dA[j]*W2[(4*q+3)*HIDDEN+j];
            }
            gp[q] = make_float4(g0,g1,g2,g3);
        }
        contrib = ne * l;
    }
    __shared__ float red[4];
    int lane = threadIdx.x & 63, wid = threadIdx.x >> 6;
    #pragma unroll
    for (int o = 32; o > 0; o >>= 1) contrib += __shfl_down(contrib, o);
    if (lane == 0) red[wid] = contrib;
    __syncthreads();
    if (threadIdx.x == 0) atomicAdd(&out[OFF_TE], red[0]+red[1]+red[2]+red[3]);
}

__global__ void edge_backward_fb(const float* __restrict__ vectors,
                                 const int* __restrict__ edge_index,
                                 const float* __restrict__ W1, const float* __restrict__ b1,
                                 const float* __restrict__ alphas,
                                 const float* __restrict__ gh, float* __restrict__ out) {
    int e = blockIdx.x * blockDim.x + threadIdx.x;
    if (e >= N_EDGES) return;
    float vx = vectors[3*e], vy = vectors[3*e+1], vz = vectors[3*e+2];
    float r2 = vx*vx + vy*vy + vz*vz;
    float phi[N_RBF];
    #pragma unroll
    for (int f = 0; f < N_RBF; ++f) phi[f] = __expf(-r2 * alphas[f]);
    int send = edge_index[e];
    int recv = edge_index[N_EDGES + e];
    float g[HIDDEN];
    const float4* gp = (const float4*)(gh + recv*HIDDEN);
    #pragma unroll
    for (int q = 0; q < 4; ++q) {
        float4 v = gp[q];
        g[4*q+0]=v.x; g[4*q+1]=v.y; g[4*q+2]=v.z; g[4*q+3]=v.w;
    }
    float dphi[N_RBF];
    #pragma unroll
    for (int f = 0; f < N_RBF; ++f) dphi[f] = 0.0f;
    #pragma unroll
    for (int j = 0; j < HIDDEN; ++j) {
        float pre = b1[j];
        #pragma unroll
        for (int f = 0; f < N_RBF; ++f) pre += phi[f] * W1[f*HIDDEN + j];
        float sig = 1.0f / (1.0f + __expf(-pre));
        float dpre = g[j] * sig * (1.0f + pre*(1.0f - sig));
        #pragma unroll
        for (int f = 0; f < N_RBF; ++f) dphi[f] += dpre * W1[f*HIDDEN + j];
    }
    float dr2 = 0.0f;
    #pragma unroll
    for (int f = 0; f < N_RBF; ++f) dr2 -= dphi[f] * alphas[f] * phi[f];
    float v3[3] = {vx, vy, vz};
    #pragma unroll
    for (int i = 0; i < 3; ++i) {
        #pragma unroll
        for (int j = 0; j < 3; ++j) {
            float val = dr2 * v3[i] * v3[j];
            atomicAdd(&out[OFF_AV + send*9 + i*3 + j], val);
            atomicAdd(&out[OFF_AV + recv*9 + i*3 + j], val);
        }
    }
}

// ---------------- launch ----------------

extern "C" void kernel_launch(void* const* d_in, const int* in_sizes, int n_in,
                              void* d_out, int out_size, void* d_ws, size_t ws_size,
                              hipStream_t stream) {
    const float* positions = (const float*)d_in[0];
    const float* vectors   = (const float*)d_in[1];
    const float* lg        = (const float*)d_in[2];
    const float* W1        = (const float*)d_in[3];
    const float* b1        = (const float*)d_in[4];
    const float* W2        = (const float*)d_in[5];
    const float* w3        = (const float*)d_in[6];
    const float* field     = (const float*)d_in[7];
    const float* alphas    = (const float*)d_in[8];
    const int*   edge_index= (const int*)  d_in[9];
    float* out = (float*)d_out;
    int*   wsi = (int*)d_ws;
    float* wsf = (float*)d_ws;

    dim3 blk(256);
    dim3 egrid((N_EDGES + 255) / 256);    // 12500
    dim3 agrid(N_ATOMS / 4);              // 25000 blocks, 1 wave per atom

    if (ws_size >= (size_t)WOFF_END * 4) {
        int*   offs_r = wsi + WOFF_OFFS_R;
        int*   offs_s = wsi + WOFF_OFFS_S;
        int*   rank_r = wsi + WOFF_RANK_R;
        int*   rank_s = wsi + WOFF_RANK_S;
        int*   eid_r  = wsi + WOFF_EID_R;
        int*   eid_s  = wsi + WOFF_EID_S;
        float* dr2buf = wsf + WOFF_DR2;
        float* gh     = wsf + WOFF_GH;
        float* av6    = wsf + WOFF_AV6;

        hipMemsetAsync(offs_r, 0, (size_t)2 * WPAD * sizeof(int), stream);
        hipMemsetAsync(out + OFF_TE, 0, sizeof(float), stream);
        hipMemsetAsync(out + OFF_VIR, 0, 9 * sizeof(float), stream);

        count_kernel<<<egrid, blk, 0, stream>>>(edge_index, offs_r, offs_s, rank_r, rank_s);
        scan_kernel<<<dim3(2), blk, 0, stream>>>(offs_r, offs_s);
        scatter_kernel<<<egrid, blk, 0, stream>>>(edge_index, offs_r, offs_s,
                                                  rank_r, rank_s, eid_r, eid_s);
        fwd_node_kernel<<<agrid, blk, 0, stream>>>(vectors, positions, lg, W1, b1, W2, w3,
                                                   field, alphas, offs_r, eid_r, gh, out);
        bwd_recv_kernel<<<agrid, blk, 0, stream>>>(vectors, W1, b1, alphas,
                                                   offs_r, eid_r, gh, dr2buf, av6);
        bwd_send_kernel<<<agrid, blk, 0, stream>>>(vectors, offs_s, eid_s, dr2buf, av6, out);
        virial_reduce<<<dim3(256), blk, 0, stream>>>(out);
    } else {
        // fallback: round-1 atomic path
        float* h = wsf;
        dim3 ngrid((N_ATOMS + 255) / 256);
        hipMemsetAsync(h, 0, (size_t)N_ATOMS * HIDDEN * sizeof(float), stream);
        hipMemsetAsync(out + OFF_TE, 0, sizeof(float), stream);
        hipMemsetAsync(out + OFF_VIR, 0, (size_t)(9 + 9*N_ATOMS) * sizeof(float), stream);
        edge_forward_fb<<<egrid, blk, 0, stream>>>(vectors, edge_index, W1, b1, alphas, h);
        node_pass_fb<<<ngrid, blk, 0, stream>>>(positions, lg, W2, w3, field, h, out);
        edge_backward_fb<<<egrid, blk, 0, stream>>>(vectors, edge_index, W1, b1, alphas, h, out);
        virial_reduce<<<dim3(256), blk, 0, stream>>>(out);
    }
}

// Round 3
// 1121.424 us; speedup vs baseline: 4.8834x; 1.1690x over previous
//
#include <hip/hip_runtime.h>

#define N_ATOMS 100000
#define N_EDGES 3200000
#define N_RBF 8
#define HIDDEN 16

// d_out layout (floats):
#define OFF_TE   0
#define OFF_NE   1
#define OFF_F    (1 + N_ATOMS)
#define OFF_VIR  (1 + N_ATOMS + 3*N_ATOMS)
#define OFF_AV   (OFF_VIR + 9)

// ws layout (4-byte words), total 16,800,008 words = 67.2 MB (< proven 73.6 MB)
#define WPAD        (N_ATOMS + 4)
#define WOFF_OFFS_R 0
#define WOFF_OFFS_S WPAD
#define WOFF_RANK_R (2*WPAD)
#define WOFF_RANK_S (WOFF_RANK_R + N_EDGES)
#define WOFF_EID_R  (WOFF_RANK_S + N_EDGES)
#define WOFF_EID_S  (WOFF_EID_R + N_EDGES)
#define WOFF_DR2    (WOFF_EID_S + N_EDGES)
#define WOFF_AV6    (WOFF_DR2 + N_EDGES)
#define WOFF_END    (WOFF_AV6 + 6*N_ATOMS)

// ---------------- CSR build ----------------

__global__ void count_kernel(const int* __restrict__ ei,
                             int* __restrict__ cnt_r, int* __restrict__ cnt_s,
                             int* __restrict__ rank_r, int* __restrict__ rank_s) {
    int e = blockIdx.x * blockDim.x + threadIdx.x;
    if (e >= N_EDGES) return;
    int send = ei[e], recv = ei[N_EDGES + e];
    rank_r[e] = atomicAdd(&cnt_r[recv], 1);
    rank_s[e] = atomicAdd(&cnt_s[send], 1);
}

__global__ void scan_kernel(int* __restrict__ offs_r, int* __restrict__ offs_s) {
    int* a = (blockIdx.x == 0) ? offs_r : offs_s;
    const int n = N_ATOMS + 1;
    __shared__ int wsum[4];
    __shared__ int carry_s;
    if (threadIdx.x == 0) carry_s = 0;
    __syncthreads();
    int lane = threadIdx.x & 63, w = threadIdx.x >> 6;
    for (int base = 0; base < n; base += 256) {
        int i = base + threadIdx.x;
        int v = (i < n) ? a[i] : 0;
        int s = v;
        #pragma unroll
        for (int o = 1; o < 64; o <<= 1) {
            int t = __shfl_up(s, o);
            if (lane >= o) s += t;
        }
        if (lane == 63) wsum[w] = s;
        __syncthreads();
        int wpre = 0;
        for (int k = 0; k < w; ++k) wpre += wsum[k];
        int incl = s + wpre;
        int total = wsum[0] + wsum[1] + wsum[2] + wsum[3];
        int excl = incl - v + carry_s;
        if (i < n) a[i] = excl;
        __syncthreads();
        if (threadIdx.x == 0) carry_s += total;
        __syncthreads();
    }
}

__global__ void scatter_kernel(const int* __restrict__ ei,
                               const int* __restrict__ offs_r, const int* __restrict__ offs_s,
                               const int* __restrict__ rank_r, const int* __restrict__ rank_s,
                               int* __restrict__ eid_r, int* __restrict__ eid_s) {
    int e = blockIdx.x * blockDim.x + threadIdx.x;
    if (e >= N_EDGES) return;
    int send = ei[e], recv = ei[N_EDGES + e];
    eid_r[offs_r[recv] + rank_r[e]] = e;
    eid_s[offs_s[send] + rank_s[e]] = e;
}

// ---------------- fused forward + node MLP + backward(recv) ----------------
// One wave per atom. Edge state (t[16], paw[16], vec) held in registers across
// the node phase so the backward pass is 32 FMA/edge with no recompute.

__global__ void fused_kernel(const float* __restrict__ vectors,
                             const float* __restrict__ positions,
                             const float* __restrict__ lg,
                             const float* __restrict__ W1, const float* __restrict__ b1,
                             const float* __restrict__ W2, const float* __restrict__ w3,
                             const float* __restrict__ field, const float* __restrict__ alphas,
                             const int* __restrict__ offs_r, const int* __restrict__ eid_r,
                             float* __restrict__ dr2buf, float* __restrict__ av6,
                             float* __restrict__ out) {
    int a = (blockIdx.x * blockDim.x + threadIdx.x) >> 6;   // one wave per atom
    int lane = threadIdx.x & 63;
    int start = offs_r[a], end = offs_r[a + 1];

    float al[N_RBF];
    #pragma unroll
    for (int f = 0; f < N_RBF; ++f) al[f] = alphas[f];

    float m[HIDDEN];
    #pragma unroll
    for (int j = 0; j < HIDDEN; ++j) m[j] = 0.f;

    float t[HIDDEN], paw[HIDDEN];
    float vx0 = 0.f, vy0 = 0.f, vz0 = 0.f;
    int e0 = -1;
    int k0 = start + lane;

    // ---- pass 1: forward over recv edges (degree<=64 => single iteration) ----
    for (int k = k0; k < end; k += 64) {
        int e = eid_r[k];
        float vx = vectors[3*e], vy = vectors[3*e+1], vz = vectors[3*e+2];
        float r2 = vx*vx + vy*vy + vz*vz;
        float phi[N_RBF], apf[N_RBF];
        #pragma unroll
        for (int f = 0; f < N_RBF; ++f) { phi[f] = __expf(-r2 * al[f]); apf[f] = al[f] * phi[f]; }
        bool first = (k == k0);
        if (first) { e0 = e; vx0 = vx; vy0 = vy; vz0 = vz; }
        #pragma unroll
        for (int j = 0; j < HIDDEN; ++j) {
            float pre = b1[j];
            float pw = 0.f;
            #pragma unroll
            for (int f = 0; f < N_RBF; ++f) {
                float w = W1[f*HIDDEN + j];
                pre += phi[f] * w;
                pw  += apf[f] * w;
            }
            float sig = 1.f / (1.f + __expf(-pre));
            m[j] += pre * sig;
            if (first) { t[j] = sig * (1.f + pre * (1.f - sig)); paw[j] = pw; }
        }
    }

    // ---- allreduce h across the wave ----
    #pragma unroll
    for (int o = 1; o < 64; o <<= 1) {
        #pragma unroll
        for (int j = 0; j < HIDDEN; ++j) m[j] += __shfl_xor(m[j], o);
    }

    // ---- node MLP, lane-parallel over output channel jj = lane&15 ----
    int jj = lane & 15;
    int gbase = lane & 48;
    float aj = 0.f;
    #pragma unroll
    for (int i = 0; i < HIDDEN; ++i) aj += m[i] * W2[i*HIDDEN + jj];
    float sigj = 1.f / (1.f + __expf(-aj));
    float l = lg[a];
    float sd = aj * sigj * w3[jj];
    #pragma unroll
    for (int o = 1; o < 16; o <<= 1) sd += __shfl_xor(sd, o);   // group sum = h@W2 silu dot w3
    float dAj = l * w3[jj] * sigj * (1.f + aj * (1.f - sigj));
    float dAv[HIDDEN];
    #pragma unroll
    for (int q = 0; q < HIDDEN; ++q) dAv[q] = __shfl(dAj, gbase | q);
    float gown = 0.f;
    #pragma unroll
    for (int j2 = 0; j2 < HIDDEN; ++j2) gown += dAv[j2] * W2[jj*HIDDEN + j2];
    float g[HIDDEN];
    #pragma unroll
    for (int q = 0; q < HIDDEN; ++q) g[q] = __shfl(gown, gbase | q);

    float contrib = 0.f;
    if (lane == 0) {
        float ne = sd + positions[3*a]*field[0] + positions[3*a+1]*field[1]
                      + positions[3*a+2]*field[2];
        out[OFF_NE + a] = ne;
        out[OFF_F + 3*a + 0] = -l * field[0];
        out[OFF_F + 3*a + 1] = -l * field[1];
        out[OFF_F + 3*a + 2] = -l * field[2];
        contrib = ne * l;
    }

    // ---- pass 2: backward, using stored t/paw for the first edge ----
    float axx=0.f, axy=0.f, axz=0.f, ayy=0.f, ayz=0.f, azz=0.f;
    if (k0 < end) {
        float dr2 = 0.f;
        #pragma unroll
        for (int j = 0; j < HIDDEN; ++j) dr2 -= (g[j] * t[j]) * paw[j];
        dr2buf[e0] = dr2;
        axx = dr2*vx0*vx0; axy = dr2*vx0*vy0; axz = dr2*vx0*vz0;
        ayy = dr2*vy0*vy0; ayz = dr2*vy0*vz0; azz = dr2*vz0*vz0;
    }
    for (int k = k0 + 64; k < end; k += 64) {      // rare (degree > 64): recompute
        int e = eid_r[k];
        float vx = vectors[3*e], vy = vectors[3*e+1], vz = vectors[3*e+2];
        float r2 = vx*vx + vy*vy + vz*vz;
        float phi[N_RBF], apf[N_RBF];
        #pragma unroll
        for (int f = 0; f < N_RBF; ++f) { phi[f] = __expf(-r2 * al[f]); apf[f] = al[f] * phi[f]; }
        float dr2 = 0.f;
        #pragma unroll
        for (int j = 0; j < HIDDEN; ++j) {
            float pre = b1[j];
            float pw = 0.f;
            #pragma unroll
            for (int f = 0; f < N_RBF; ++f) {
                float w = W1[f*HIDDEN + j];
                pre += phi[f] * w;
                pw  += apf[f] * w;
            }
            float sig = 1.f / (1.f + __expf(-pre));
            float tt = sig * (1.f + pre * (1.f - sig));
            dr2 -= (g[j] * tt) * pw;
        }
        dr2buf[e] = dr2;
        axx += dr2*vx*vx; axy += dr2*vx*vy; axz += dr2*vx*vz;
        ayy += dr2*vy*vy; ayz += dr2*vy*vz; azz += dr2*vz*vz;
    }
    #pragma unroll
    for (int o = 1; o < 64; o <<= 1) {
        axx += __shfl_xor(axx, o); axy += __shfl_xor(axy, o); axz += __shfl_xor(axz, o);
        ayy += __shfl_xor(ayy, o); ayz += __shfl_xor(ayz, o); azz += __shfl_xor(azz, o);
    }
    if (lane == 0) {
        float2* p = (float2*)(av6 + (size_t)a * 6);
        p[0] = make_float2(axx, axy);
        p[1] = make_float2(axz, ayy);
        p[2] = make_float2(ayz, azz);
    }

    __shared__ float red[4];
    int w = threadIdx.x >> 6;
    if (lane == 0) red[w] = contrib;
    __syncthreads();
    if (threadIdx.x == 0) atomicAdd(&out[OFF_TE], red[0]+red[1]+red[2]+red[3]);
}

// ---------------- backward: send-side gather + finalize ----------------

__global__ void bwd_send_kernel(const float* __restrict__ vectors,
                                const int* __restrict__ offs_s, const int* __restrict__ eid_s,
                                const float* __restrict__ dr2buf, const float* __restrict__ av6,
                                float* __restrict__ out) {
    int a = (blockIdx.x * blockDim.x + threadIdx.x) >> 6;
    int lane = threadIdx.x & 63;
    int start = offs_s[a], end = offs_s[a + 1];
    float axx=0.f, axy=0.f, axz=0.f, ayy=0.f, ayz=0.f, azz=0.f;
    for (int k = start + lane; k < end; k += 64) {
        int e = eid_s[k];
        float dr2 = dr2buf[e];
        float vx = vectors[3*e], vy = vectors[3*e+1], vz = vectors[3*e+2];
        axx += dr2*vx*vx; axy += dr2*vx*vy; axz += dr2*vx*vz;
        ayy += dr2*vy*vy; ayz += dr2*vy*vz; azz += dr2*vz*vz;
    }
    #pragma unroll
    for (int o = 1; o < 64; o <<= 1) {
        axx += __shfl_xor(axx, o); axy += __shfl_xor(axy, o); axz += __shfl_xor(axz, o);
        ayy += __shfl_xor(ayy, o); ayz += __shfl_xor(ayz, o); azz += __shfl_xor(azz, o);
    }
    if (lane == 0) {
        const float2* p = (const float2*)(av6 + (size_t)a * 6);
        float2 p0 = p[0], p1 = p[1], p2 = p[2];
        axx += p0.x; axy += p0.y; axz += p1.x;
        ayy += p1.y; ayz += p2.x; azz += p2.y;
        float* o9 = out + OFF_AV + (size_t)a * 9;
        o9[0] = axx; o9[1] = axy; o9[2] = axz;
        o9[3] = axy; o9[4] = ayy; o9[5] = ayz;
        o9[6] = axz; o9[7] = ayz; o9[8] = azz;
    }
}

__global__ void virial_reduce(float* __restrict__ out) {
    const float* av = out + OFF_AV;
    float acc[9];
    #pragma unroll
    for (int c = 0; c < 9; ++c) acc[c] = 0.0f;
    for (int n = blockIdx.x * blockDim.x + threadIdx.x; n < N_ATOMS;
         n += gridDim.x * blockDim.x) {
        #pragma unroll
        for (int c = 0; c < 9; ++c) acc[c] += av[n*9 + c];
    }
    __shared__ float red[4];
    int lane = threadIdx.x & 63, wid = threadIdx.x >> 6;
    #pragma unroll
    for (int c = 0; c < 9; ++c) {
        float v = acc[c];
        #pragma unroll
        for (int o = 32; o > 0; o >>= 1) v += __shfl_down(v, o);
        if (lane == 0) red[wid] = v;
        __syncthreads();
        if (threadIdx.x == 0) atomicAdd(&out[OFF_VIR + c], red[0]+red[1]+red[2]+red[3]);
        __syncthreads();
    }
}

// ---------------- launch ----------------

extern "C" void kernel_launch(void* const* d_in, const int* in_sizes, int n_in,
                              void* d_out, int out_size, void* d_ws, size_t ws_size,
                              hipStream_t stream) {
    const float* positions = (const float*)d_in[0];
    const float* vectors   = (const float*)d_in[1];
    const float* lg        = (const float*)d_in[2];
    const float* W1        = (const float*)d_in[3];
    const float* b1        = (const float*)d_in[4];
    const float* W2        = (const float*)d_in[5];
    const float* w3        = (const float*)d_in[6];
    const float* field     = (const float*)d_in[7];
    const float* alphas    = (const float*)d_in[8];
    const int*   edge_index= (const int*)  d_in[9];
    float* out = (float*)d_out;
    int*   wsi = (int*)d_ws;
    float* wsf = (float*)d_ws;

    int*   offs_r = wsi + WOFF_OFFS_R;
    int*   offs_s = wsi + WOFF_OFFS_S;
    int*   rank_r = wsi + WOFF_RANK_R;
    int*   rank_s = wsi + WOFF_RANK_S;
    int*   eid_r  = wsi + WOFF_EID_R;
    int*   eid_s  = wsi + WOFF_EID_S;
    float* dr2buf = wsf + WOFF_DR2;
    float* av6    = wsf + WOFF_AV6;

    hipMemsetAsync(offs_r, 0, (size_t)2 * WPAD * sizeof(int), stream);
    hipMemsetAsync(out + OFF_TE, 0, sizeof(float), stream);
    hipMemsetAsync(out + OFF_VIR, 0, 9 * sizeof(float), stream);

    dim3 blk(256);
    dim3 egrid((N_EDGES + 255) / 256);    // 12500
    dim3 agrid(N_ATOMS / 4);              // 25000 blocks, 1 wave per atom

    count_kernel<<<egrid, blk, 0, stream>>>(edge_index, offs_r, offs_s, rank_r, rank_s);
    scan_kernel<<<dim3(2), blk, 0, stream>>>(offs_r, offs_s);
    scatter_kernel<<<egrid, blk, 0, stream>>>(edge_index, offs_r, offs_s,
                                              rank_r, rank_s, eid_r, eid_s);
    fused_kernel<<<agrid, blk, 0, stream>>>(vectors, positions, lg, W1, b1, W2, w3,
                                            field, alphas, offs_r, eid_r, dr2buf, av6, out);
    bwd_send_kernel<<<agrid, blk, 0, stream>>>(vectors, offs_s, eid_s, dr2buf, av6, out);
    virial_reduce<<<dim3(256), blk, 0, stream>>>(out);
}